// Round 5
// baseline (172.895 us; speedup 1.0000x reference)
//
#include <hip/hip_runtime.h>

// DMoE (PLE/CGC) fused kernel for MI355X (gfx950).
// B=32768, D_IN=256, H=128, N_TASK=2, N_EXP=4, N_SHARE=4.
//
// R12: weights-resident, barrier-free rewrite. R7/R9/R11 all convoy on the
// stage->barrier->burst->barrier structure (~600-cyc steps, <250 cyc work;
// every pipe <25% busy regardless of occupancy or pipeline depth). Key fact:
// per (task, h16-slice) ALL 8 experts' weights = 64 KB = 256 regs = one
// wave's AGPR file. So:
//  - 256 blocks x 256 thr, __launch_bounds__(256,1): 1 wave/SIMD, ~450 regs.
//  - wave owns (t, h16): 8 expert B-frag sets resident in AGPRs (asm "+a",
//    R9-proven), gate frags + biases resident in VGPRs.
//  - x streams in 16-row m-tiles, depth-1 f32 prefetch (64 VGPR), 72 MFMAs
//    per tile in 4-5 interleaved acc chains, in-wave softmax, per-wave LDS
//    gate buffer (within-wave ordering only).
//  - ZERO __syncthreads / s_barrier in the whole kernel.
// prep emits the MFMA-frag-ordered weight image (mirror of the verified LDS
// B-frag layout: lane(quad,col), elem j <- W[kk*32+quad*8+j][h0+col]).

typedef __attribute__((ext_vector_type(8))) short short8;   // 8 x bf16
typedef __attribute__((ext_vector_type(4))) float float4v;  // MFMA C/D

#define WF_GOFF_US 393216     // 12 experts * 8 h16 * 8 kk * 512 us
#define WS_NEED_B  802816     // + 16*256 gate ushorts

__device__ __forceinline__ unsigned short f2bf(float f) {
  unsigned u = __builtin_bit_cast(unsigned, f);
  u += 0x7FFFu + ((u >> 16) & 1u);   // round-to-nearest-even
  return (unsigned short)(u >> 16);
}

__device__ __forceinline__ int slot2e(int sr, int t) {
  return (sr < 4) ? sr : 4 + t * 4 + (sr - 4);
}

// ---------------------------------------------------------------------------
// Prep: WF[e(12)][h16(8)][kk(8)][lane(64)][8 bf16] fragment image + WgT[16][256].
// Element (e,h16,kk,lane=quad*16+col,j) = W_e[kk*32+quad*8+j][h16*16+col].
__global__ __launch_bounds__(256)
void prep_kernel(const float* __restrict__ Ws,
                 const float* __restrict__ Wt,
                 const float* __restrict__ Wg,
                 unsigned short* __restrict__ WT) {
  int bid = blockIdx.x;
  int tid = threadIdx.x;
  if (bid < 96) {
    int e = bid >> 3, h16 = bid & 7;
    const float* src = (e < 4) ? Ws + ((size_t)e << 15)
                               : Wt + ((size_t)(e - 4) << 15);
    int k = tid;                       // one thread per k-row
    int kk = k >> 5, quad = (k >> 3) & 3, j = k & 7;
    size_t eb = ((size_t)(e * 8 + h16) * 8 + kk) * 512 + (size_t)quad * 128 + j;
    const float* sp = src + (size_t)k * 128 + h16 * 16;
    #pragma unroll
    for (int c4 = 0; c4 < 4; ++c4) {
      float4 v = *(const float4*)(sp + c4 * 4);
      WT[eb + (size_t)(c4 * 4 + 0) * 8] = f2bf(v.x);
      WT[eb + (size_t)(c4 * 4 + 1) * 8] = f2bf(v.y);
      WT[eb + (size_t)(c4 * 4 + 2) * 8] = f2bf(v.z);
      WT[eb + (size_t)(c4 * 4 + 3) * 8] = f2bf(v.w);
    }
  } else {
    // gate weights WgT[n][256], n = t*8+g
    #pragma unroll
    for (int it = 0; it < 16; ++it) {
      int jj = it * 256 + tid;
      int n = jj >> 8, k = jj & 255;
      int tt = n >> 3, g = n & 7;
      WT[WF_GOFF_US + jj] = f2bf(Wg[(size_t)(tt * 256 + k) * 8 + g]);
    }
  }
}

// ---------------------------------------------------------------------------
__global__ __launch_bounds__(256)
void dmoe_main(const float* __restrict__ x,
               const unsigned short* __restrict__ WT,
               const float* __restrict__ b_share,
               const float* __restrict__ b_task,
               const float* __restrict__ b_gate,
               float* __restrict__ out) {
  __shared__ float gw[4][8][20];       // per-wave [slot][16 rows] gates (2.5 KB)

  const int tid  = threadIdx.x;
  const int lane = tid & 63;
  const int w    = tid >> 6;           // wave 0..3
  const int col  = lane & 15;
  const int quad = lane >> 4;
  const int blk  = blockIdx.x;
  const int t    = blk & 1;            // task
  const int hh   = (blk >> 1) & 1;     // h half
  const int rg   = blk >> 2;           // 512-row group (0..63)
  const int h16  = hh * 4 + w;         // global h16 slice 0..7
  const int h0   = h16 * 16;

  // ---- resident expert B-fragments: 8 slots x 8 k-steps -> AGPRs ----
  short8 wf[8][8];
  #pragma unroll
  for (int sr = 0; sr < 8; ++sr) {
    const int e = slot2e(sr, t);
    const unsigned short* p = WT + ((size_t)(e * 8 + h16) * 8) * 512
                            + (size_t)lane * 8;
    #pragma unroll
    for (int kk = 0; kk < 8; ++kk) {
      wf[sr][kk] = *(const short8*)(p + (size_t)kk * 512);
      asm volatile("" : "+a"(wf[sr][kk]));   // pin to AGPR (R9-proven)
    }
  }

  // ---- resident gate B-fragments (VGPR) + gate bias ----
  short8 Bg[8];
  {
    const unsigned short* bp = WT + WF_GOFF_US
                             + (size_t)(t * 8 + (col & 7)) * 256 + quad * 8;
    #pragma unroll
    for (int kk = 0; kk < 8; ++kk) Bg[kk] = *(const short8*)(bp + kk * 32);
  }
  const float bg = b_gate[t * 8 + (col & 7)];

  // ---- resident biases for this lane's h column ----
  float bias_r[8];
  #pragma unroll
  for (int sr = 0; sr < 8; ++sr)
    bias_r[sr] = (sr < 4) ? b_share[sr * 128 + h0 + col]
                          : b_task[(size_t)(t * 4 + (sr - 4)) * 128 + h0 + col];

  const float* xb = x + ((size_t)rg * 512 + col) * 256 + quad * 8;
  float* ob = out + ((size_t)t << 22)
            + ((size_t)rg * 512 + quad * 4) * 128 + h0 + col;

  // ---- prefetch m-tile 0 (raw f32) ----
  uint4 pr[16];
  #pragma unroll
  for (int ks = 0; ks < 8; ++ks) {
    pr[2 * ks]     = *(const uint4*)(xb + ks * 32);
    pr[2 * ks + 1] = *(const uint4*)(xb + ks * 32 + 4);
  }

  // ---- 32 m-tiles of 16 rows; no barriers anywhere ----
  #pragma unroll 1
  for (int mi = 0; mi < 32; ++mi) {
    // convert prefetched raws -> A fragments (RNE, same numerics as R7)
    short8 A[8];
    #pragma unroll
    for (int ks = 0; ks < 8; ++ks) {
      float4v u = __builtin_bit_cast(float4v, pr[2 * ks]);
      float4v v = __builtin_bit_cast(float4v, pr[2 * ks + 1]);
      short8 fr;
      fr[0] = (short)f2bf(u[0]); fr[1] = (short)f2bf(u[1]);
      fr[2] = (short)f2bf(u[2]); fr[3] = (short)f2bf(u[3]);
      fr[4] = (short)f2bf(v[0]); fr[5] = (short)f2bf(v[1]);
      fr[6] = (short)f2bf(v[2]); fr[7] = (short)f2bf(v[3]);
      A[ks] = fr;
    }
    // issue next tile's loads (depth-1 prefetch; covered by ~450cy compute)
    if (mi < 31) {
      const float* xn = xb + (size_t)(mi + 1) * (16 * 256);
      #pragma unroll
      for (int ks = 0; ks < 8; ++ks) {
        pr[2 * ks]     = *(const uint4*)(xn + ks * 32);
        pr[2 * ks + 1] = *(const uint4*)(xn + ks * 32 + 4);
      }
    }

    float4v acc[8];
    #pragma unroll
    for (int i = 0; i < 8; ++i) acc[i] = (float4v){0.f, 0.f, 0.f, 0.f};

    // group 0: gate + slots 0..3 (5 interleaved MFMA chains)
    float4v ag = {0.f, 0.f, 0.f, 0.f};
    #pragma unroll
    for (int ks = 0; ks < 8; ++ks) {
      ag     = __builtin_amdgcn_mfma_f32_16x16x32_bf16(A[ks], Bg[ks],     ag,     0, 0, 0);
      acc[0] = __builtin_amdgcn_mfma_f32_16x16x32_bf16(A[ks], wf[0][ks], acc[0], 0, 0, 0);
      acc[1] = __builtin_amdgcn_mfma_f32_16x16x32_bf16(A[ks], wf[1][ks], acc[1], 0, 0, 0);
      acc[2] = __builtin_amdgcn_mfma_f32_16x16x32_bf16(A[ks], wf[2][ks], acc[2], 0, 0, 0);
      acc[3] = __builtin_amdgcn_mfma_f32_16x16x32_bf16(A[ks], wf[3][ks], acc[3], 0, 0, 0);
    }

    // softmax over the 8 gate cols; transposed store into per-wave LDS
    {
      float ps[4];
      #pragma unroll
      for (int r = 0; r < 4; ++r) {
        float vlog = ag[r] + bg;
        float m = vlog;
        m = fmaxf(m, __shfl_xor(m, 1));
        m = fmaxf(m, __shfl_xor(m, 2));
        m = fmaxf(m, __shfl_xor(m, 4));
        float pe = __expf(vlog - m);
        float ss = pe;
        ss += __shfl_xor(ss, 1);
        ss += __shfl_xor(ss, 2);
        ss += __shfl_xor(ss, 4);
        ps[r] = pe / ss;
      }
      if (col < 8) {
        float4 gv = {ps[0], ps[1], ps[2], ps[3]};
        *(float4*)&gw[w][col][quad * 4] = gv;   // same-wave readers only
      }
    }

    // group 1: slots 4..7 (4 interleaved chains)
    #pragma unroll
    for (int ks = 0; ks < 8; ++ks) {
      acc[4] = __builtin_amdgcn_mfma_f32_16x16x32_bf16(A[ks], wf[4][ks], acc[4], 0, 0, 0);
      acc[5] = __builtin_amdgcn_mfma_f32_16x16x32_bf16(A[ks], wf[5][ks], acc[5], 0, 0, 0);
      acc[6] = __builtin_amdgcn_mfma_f32_16x16x32_bf16(A[ks], wf[6][ks], acc[6], 0, 0, 0);
      acc[7] = __builtin_amdgcn_mfma_f32_16x16x32_bf16(A[ks], wf[7][ks], acc[7], 0, 0, 0);
    }

    // epilogue: bias + relu + gate-weighted sum, nt store
    float ow[4] = {0.f, 0.f, 0.f, 0.f};
    #pragma unroll
    for (int sr = 0; sr < 8; ++sr) {
      float4 gv = *(const float4*)&gw[w][sr][quad * 4];   // LDS broadcast
      #pragma unroll
      for (int r = 0; r < 4; ++r) {
        float vv = fmaxf(acc[sr][r] + bias_r[sr], 0.f);
        ow[r] += ((const float*)&gv)[r] * vv;
      }
    }
    float* op = ob + (size_t)mi * (16 * 128);
    #pragma unroll
    for (int r = 0; r < 4; ++r)
      __builtin_nontemporal_store(ow[r], op + r * 128);
  }
}

// ---------------------------------------------------------------------------
extern "C" void kernel_launch(void* const* d_in, const int* in_sizes, int n_in,
                              void* d_out, int out_size, void* d_ws, size_t ws_size,
                              hipStream_t stream) {
  const float* x       = (const float*)d_in[0];
  const float* W_share = (const float*)d_in[1];
  const float* b_share = (const float*)d_in[2];
  const float* W_task  = (const float*)d_in[3];
  const float* b_task  = (const float*)d_in[4];
  const float* W_gate  = (const float*)d_in[5];
  const float* b_gate  = (const float*)d_in[6];
  float* out = (float*)d_out;
  unsigned short* WT = (unsigned short*)d_ws;

  prep_kernel<<<97, 256, 0, stream>>>(W_share, W_task, W_gate, WT);
  dmoe_main<<<256, 256, 0, stream>>>(x, WT, b_share, b_task, b_gate, out);
}